// Round 7
// baseline (239.137 us; speedup 1.0000x reference)
//
#include <hip/hip_runtime.h>

// CovLayer: X [B=64, C=256, T=2048] fp32 -> cov [B, 256, 256] fp32
// cov = (Sxy - Sx*Sy/T)/T  via bf16 MFMA Gram + MFMA-ones row/col sums.
// Round 7 = Round 6 with the LDS slab-index bug fixed (B slabs were OOB at
// indices 8/9/12/13; off-diag blocks read zeros -> mirror half was zero).
// Structure: (1) LDS row stride 36 (18 dwords -> 2-way bank aliasing, free);
// (2) symmetry: 3 blocks/batch (2 diag A==B + 1 off-diag w/ mirror store);
// (3) lgkmcnt-only barrier keeps global prefetches in flight across s_barrier.

#define NB 64
#define NC 256
#define NT 2048
#define NITER 32
#define LSTR 36                  // padded LDS row stride, bf16 elems
#define HSZ (128 * LSTR)         // elems per (op, buf, half) slab

typedef __bf16 bf16x8 __attribute__((ext_vector_type(8)));
typedef float  f32x8  __attribute__((ext_vector_type(8)));
typedef float  f32x4  __attribute__((ext_vector_type(4)));

__device__ __forceinline__ void lds_barrier() {
    // LDS-only dependency: wait lgkmcnt, NOT vmcnt -> prefetches stay in flight.
    asm volatile("s_waitcnt lgkmcnt(0)\n\ts_barrier" ::: "memory");
}

__global__ __launch_bounds__(512, 2) void cov_kernel(const float* __restrict__ X,
                                                     float* __restrict__ out) {
    // 8 slabs of 128*36 bf16: index = op*4 + buf*2 + h  (all in [0,8)).
    __shared__ __align__(16) unsigned char smem[8 * HSZ * 2];
    __bf16* S = (__bf16*)smem;

    const int bid  = blockIdx.x;     // 192 = 8 xcd * 8 batch-groups * 3 tiles
    const int xcd  = bid & 7;
    const int sidx = bid >> 3;       // 0..23
    const int b    = xcd + 8 * (sidx / 3);
    const int type = sidx % 3;       // 0: diag(0,0)  1: diag(128,128)  2: off(0,128)
    const bool offd = (type == 2);
    const int row0 = (type == 1) ? 128 : 0;
    const int col0 = (type == 0) ? 0 : 128;

    const float* __restrict__ Xb = X + (size_t)b * (NC * NT);

    const int t = threadIdx.x, lane = t & 63, wave = t >> 6;
    const int h    = wave >> 2;          // split-K half
    const int wq   = wave & 3;
    const int wm   = wq >> 1, wn = wq & 1;
    const int quad = lane >> 4, l16 = lane & 15;

    // Staging: u in [0,256): rows sr and sr+64, 8-float chunk sc.
    const int u  = t & 255;
    const int sr = u >> 2;
    const int sc = (u & 3) * 8;
    const float* gA0 = Xb + (size_t)(row0 + sr) * NT + h * (NT / 2) + sc;
    const float* gA1 = gA0 + (size_t)64 * NT;
    const float* gB0 = Xb + (size_t)(col0 + sr) * NT + h * (NT / 2) + sc;
    const float* gB1 = gB0 + (size_t)64 * NT;

    const int woff = sr * LSTR + sc;     // +64*LSTR for the twin row
    // FIXED slab indexing: A buf0/buf1 -> slabs {0+h, 2+h}; B -> {4+h, 6+h}.
    __bf16* wA[2] = { S + (0 + h) * HSZ, S + (2 + h) * HSZ };
    __bf16* wB[2] = { S + (4 + h) * HSZ, S + (6 + h) * HSZ };
    const __bf16* rA[2] = { wA[0], wA[1] };
    const __bf16* rB[2] = { offd ? (const __bf16*)wB[0] : (const __bf16*)wA[0],
                            offd ? (const __bf16*)wB[1] : (const __bf16*)wA[1] };

    f32x4 acc[4][4], accRS[4], accCS[4];
#pragma unroll
    for (int i = 0; i < 4; ++i) {
        accRS[i] = (f32x4){0.f, 0.f, 0.f, 0.f};
        accCS[i] = (f32x4){0.f, 0.f, 0.f, 0.f};
#pragma unroll
        for (int j = 0; j < 4; ++j) acc[i][j] = (f32x4){0.f, 0.f, 0.f, 0.f};
    }
    const bf16x8 ones = {(__bf16)1.0f, (__bf16)1.0f, (__bf16)1.0f, (__bf16)1.0f,
                         (__bf16)1.0f, (__bf16)1.0f, (__bf16)1.0f, (__bf16)1.0f};

    // Prologue: stage iter 0 -> buf0; prefetch iter 1 into regs.
    f32x8 pA0 = *(const f32x8*)gA0;
    f32x8 pA1 = *(const f32x8*)gA1;
    f32x8 pB0, pB1;
    if (offd) { pB0 = *(const f32x8*)gB0; pB1 = *(const f32x8*)gB1; }
    *(bf16x8*)(wA[0] + woff)             = __builtin_convertvector(pA0, bf16x8);
    *(bf16x8*)(wA[0] + woff + 64 * LSTR) = __builtin_convertvector(pA1, bf16x8);
    if (offd) {
        *(bf16x8*)(wB[0] + woff)             = __builtin_convertvector(pB0, bf16x8);
        *(bf16x8*)(wB[0] + woff + 64 * LSTR) = __builtin_convertvector(pB1, bf16x8);
    }
    pA0 = *(const f32x8*)(gA0 + 32);
    pA1 = *(const f32x8*)(gA1 + 32);
    if (offd) { pB0 = *(const f32x8*)(gB0 + 32); pB1 = *(const f32x8*)(gB1 + 32); }
    lds_barrier();

    const int aBase = (wm * 64 + l16) * LSTR + quad * 8;
    const int bBase = (wn * 64 + l16) * LSTR + quad * 8;

#pragma unroll 2
    for (int k = 0; k < NITER; ++k) {
        const int cur = k & 1, nxt = cur ^ 1;

        if (k + 1 < NITER) {             // stage G_{k+1} (vmcnt waits land here)
            *(bf16x8*)(wA[nxt] + woff)             = __builtin_convertvector(pA0, bf16x8);
            *(bf16x8*)(wA[nxt] + woff + 64 * LSTR) = __builtin_convertvector(pA1, bf16x8);
            if (offd) {
                *(bf16x8*)(wB[nxt] + woff)             = __builtin_convertvector(pB0, bf16x8);
                *(bf16x8*)(wB[nxt] + woff + 64 * LSTR) = __builtin_convertvector(pB1, bf16x8);
            }
        }
        if (k + 2 < NITER) {             // prefetch G_{k+2}: one full iter of cover
            pA0 = *(const f32x8*)(gA0 + (k + 2) * 32);
            pA1 = *(const f32x8*)(gA1 + (k + 2) * 32);
            if (offd) {
                pB0 = *(const f32x8*)(gB0 + (k + 2) * 32);
                pB1 = *(const f32x8*)(gB1 + (k + 2) * 32);
            }
        }

        bf16x8 aF[4], bF[4];
#pragma unroll
        for (int mt = 0; mt < 4; ++mt)
            aF[mt] = *(const bf16x8*)(rA[cur] + aBase + mt * 16 * LSTR);
#pragma unroll
        for (int nt = 0; nt < 4; ++nt)
            bF[nt] = *(const bf16x8*)(rB[cur] + bBase + nt * 16 * LSTR);

#pragma unroll
        for (int mt = 0; mt < 4; ++mt) {
            accRS[mt] = __builtin_amdgcn_mfma_f32_16x16x32_bf16(aF[mt], ones, accRS[mt], 0, 0, 0);
#pragma unroll
            for (int nt = 0; nt < 4; ++nt)
                acc[mt][nt] = __builtin_amdgcn_mfma_f32_16x16x32_bf16(aF[mt], bF[nt], acc[mt][nt], 0, 0, 0);
        }
#pragma unroll
        for (int nt = 0; nt < 4; ++nt)
            accCS[nt] = __builtin_amdgcn_mfma_f32_16x16x32_bf16(ones, bF[nt], accCS[nt], 0, 0, 0);

        lds_barrier();
    }

    // ---- Epilogue: combine K-halves; off-diag also mirror-stores via LDS. ----
    float* redF = (float*)smem;
    float* red  = redF + wq * (64 * 65);
    float* rs   = redF + 4 * (64 * 65);      // [4][64]
    float* cs   = rs + 256;                  // [4][64]

    if (h == 1) {
#pragma unroll
        for (int mt = 0; mt < 4; ++mt)
#pragma unroll
            for (int nt = 0; nt < 4; ++nt)
#pragma unroll
                for (int r = 0; r < 4; ++r)
                    red[(mt * 16 + quad * 4 + r) * 65 + nt * 16 + l16] = acc[mt][nt][r];
        if (l16 == 0)
#pragma unroll
            for (int mt = 0; mt < 4; ++mt)
#pragma unroll
                for (int r = 0; r < 4; ++r)
                    rs[wq * 64 + mt * 16 + quad * 4 + r] = accRS[mt][r];
        if (quad == 0)
#pragma unroll
            for (int nt = 0; nt < 4; ++nt)
                cs[wq * 64 + nt * 16 + l16] = accCS[nt][0];
    }
    __syncthreads();

    const float invT = 1.0f / NT;
    float* __restrict__ outB = out + (size_t)b * (NC * NC);

    if (h == 0) {
#pragma unroll
        for (int mt = 0; mt < 4; ++mt) {
#pragma unroll
            for (int nt = 0; nt < 4; ++nt) {
#pragma unroll
                for (int r = 0; r < 4; ++r) {
                    const int R = mt * 16 + quad * 4 + r;
                    const int C = nt * 16 + l16;
                    const float tot = red[R * 65 + C] + acc[mt][nt][r];
                    const float Sx  = rs[wq * 64 + R] + accRS[mt][r];
                    const float Sy  = cs[wq * 64 + C] + accCS[nt][0];
                    const float val = (tot - Sx * Sy * invT) * invT;
                    outB[(size_t)(row0 + wm * 64 + R) * NC + (col0 + wn * 64 + C)] = val;
                    if (offd) red[R * 65 + C] = val;   // final value for mirror pass
                }
            }
        }
    }
    if (offd) {                          // block-uniform: barrier is legal
        __syncthreads();
        if (h == 1) {                    // coalesced mirror store, transposed read
#pragma unroll
            for (int ci = 0; ci < 4; ++ci) {
#pragma unroll
                for (int rj = 0; rj < 4; ++rj) {
#pragma unroll
                    for (int e = 0; e < 4; ++e) {
                        const int C = ci * 16 + quad * 4 + e;   // output row (mirror)
                        const int R = rj * 16 + l16;            // contiguous along l16
                        outB[(size_t)(col0 + wn * 64 + C) * NC + (row0 + wm * 64 + R)] =
                            red[R * 65 + C];
                    }
                }
            }
        }
    }
}

extern "C" void kernel_launch(void* const* d_in, const int* in_sizes, int n_in,
                              void* d_out, int out_size, void* d_ws, size_t ws_size,
                              hipStream_t stream) {
    const float* X = (const float*)d_in[0];
    float* out = (float*)d_out;
    (void)in_sizes; (void)n_in; (void)out_size; (void)d_ws; (void)ws_size;
    cov_kernel<<<192, 512, 0, stream>>>(X, out);
}